// Round 9
// baseline (63.506 us; speedup 1.0000x reference)
//
#include <hip/hip_runtime.h>
#include <hip/hip_bf16.h>

// QuantumFeedForward, fully fused, register-resident H:
//   q[n,w] = prod_{v in M_w} cos(theta_v)*cos(x[n,v])   (analytic circuit collapse)
//   out    = relu(q@W1^T+b1) @ W2^T + b2
// 32x32x16 MFMA. H^T-tile = mfma(W1aug-frag, qaug-frag) -> relu -> cvt_pk ->
// v_permlane32_swap -> GEMM A-quads, all in REGISTERS (wave-private: no LDS, no
// barriers for H). Only W2 is LDS-staged, in 128-k pairs (256B rows, row&15 XOR
// swizzle pre-applied in global so linear global_load_lds yields 2-way-free reads).
// Sync: ONE vmcnt(0)+s_barrier per K-pair (16 total), stage issued post-barrier.

typedef __attribute__((ext_vector_type(8))) short bf16x8;
typedef __attribute__((ext_vector_type(16))) float f32x16;
typedef __attribute__((ext_vector_type(8))) unsigned short us8;
typedef unsigned int u32;

#define NTOK  16384
#define EMBED 512
#define FFN   2048
#define NQ    10
#define BM    128
#define BN    128

__device__ __forceinline__ unsigned short f2bf(float f) {
  union { float f; unsigned int u; } a; a.f = f;
  unsigned int r = a.u + 0x7FFFu + ((a.u >> 16) & 1u);   // RNE
  return (unsigned short)(r >> 16);
}

__device__ __forceinline__ void gload_lds16(const void* g, void* l) {
  __builtin_amdgcn_global_load_lds(
      (const __attribute__((address_space(1))) unsigned int*)g,
      (__attribute__((address_space(3))) unsigned int*)l, 16, 0, 0);
}

// ---- K0: W2 (512x2048 f32) -> bf16, 16-slot chunk-swizzled within 128-k pairs ----
__global__ __launch_bounds__(256) void k_cvt_w2(const float* __restrict__ W2,
                                                unsigned short* __restrict__ W2b) {
  int gid = blockIdx.x * 256 + threadIdx.x;     // one 8-elem chunk
  int idx = gid * 8;
  int row = idx >> 11;
  int c   = (idx >> 3) & 255;                   // chunk within row (0..255)
  int pair = c >> 4, cl = c & 15;
  int slot = cl ^ (row & 15);
  float4 v0 = *(const float4*)(W2 + idx);
  float4 v1 = *(const float4*)(W2 + idx + 4);
  us8 o;
  o[0] = f2bf(v0.x); o[1] = f2bf(v0.y); o[2] = f2bf(v0.z); o[3] = f2bf(v0.w);
  o[4] = f2bf(v1.x); o[5] = f2bf(v1.y); o[6] = f2bf(v1.z); o[7] = f2bf(v1.w);
  *(us8*)(W2b + (size_t)row * FFN + pair * 128 + slot * 8) = o;
}

// ---- K0b: W1_aug -> bf16 A-frag order for 32x32x16 ----
// W1f[blk][lane][e] = W1aug[wire=(lane>>5)*8+e][k = blk*32 + (lane&31)]
__global__ __launch_bounds__(256) void k_cvt_w1f(const float* __restrict__ W1,
                                                 const float* __restrict__ b1,
                                                 unsigned short* __restrict__ W1f) {
  int gid = blockIdx.x * 256 + threadIdx.x;     // 4096 = 64 blk * 64 lanes
  int l = gid & 63, blk = gid >> 6;
  int k = blk * 32 + (l & 31);
  int wg = (l >> 5) * 8;
  us8 o;
#pragma unroll
  for (int e = 0; e < 8; ++e) {
    int wire = wg + e;
    float v = (wire < NQ) ? W1[k * NQ + wire] : (wire == NQ ? b1[k] : 0.f);
    o[e] = f2bf(v);
  }
  *(us8*)(W1f + (size_t)gid * 8) = o;
}

// ---- K0c: q_aug B-frags for 32x32x16 ----
// Qf[tile][lane][e] = qaug[wire=(lane>>5)*8+e][token = tile*32 + (lane&31)]
__global__ __launch_bounds__(256) void k_q(const float* __restrict__ x,
                                           const float* __restrict__ theta,
                                           unsigned short* __restrict__ Qf) {
  int gid = blockIdx.x * 256 + threadIdx.x;     // 32768 = 512 tiles * 64 lanes
  int l = gid & 63, tile = gid >> 6;
  int tok = tile * 32 + (l & 31), g = l >> 5;
  const int masks[NQ] = {0x2AB,0x3FD,0x3FA,0x3F5,0x3EA,0x3D5,0x3AA,0x355,0x2AA,0x155};
  float z[NQ], qv[NQ];
#pragma unroll
  for (int w = 0; w < NQ; ++w)
    z[w] = __builtin_cosf(x[(size_t)tok * EMBED + w]) * __builtin_cosf(theta[w]);
#pragma unroll
  for (int w = 0; w < NQ; ++w) {
    float p = 1.f;
#pragma unroll
    for (int v = 0; v < NQ; ++v)
      if ((masks[w] >> v) & 1) p *= z[v];
    qv[w] = p;
  }
  us8 o = (us8)0;
  if (g == 0) {
#pragma unroll
    for (int e = 0; e < 8; ++e) o[e] = f2bf(qv[e]);
  } else {
    o[0] = f2bf(qv[8]); o[1] = f2bf(qv[9]); o[2] = f2bf(1.f);
  }
  *(us8*)(Qf + (size_t)gid * 8) = o;
}

// ---------------- K1: fused H-gen(MFMA, reg-resident) + GEMM ----------------
__global__ __launch_bounds__(256, 2) void k_fused(const unsigned short* __restrict__ Qf,
                                                  const unsigned short* __restrict__ W1f,
                                                  const unsigned short* __restrict__ W2b,
                                                  const float* __restrict__ b2,
                                                  float* __restrict__ out) {
  __shared__ short Bw[2][128 * 128];   // 64KB: two 128-k-pair W2 tiles

  // XCD-aware bijective swizzle: 512 blocks, 64 consecutive per XCD; n fastest.
  int bid = blockIdx.x;
  int swz = (bid & 7) * 64 + (bid >> 3);
  const int m0 = (swz >> 2) * BM;
  const int n0 = (swz & 3) * BN;
  const int tid  = threadIdx.x;
  const int lane = tid & 63;
  const int wave = tid >> 6;           // 4 waves: 2 (M) x 2 (N), 64x64 tiles
  const int wm = wave >> 1, wn = wave & 1;
  const int h = lane >> 5, t31 = lane & 31;

  // q_aug B-frags for this wave's 2 token-tiles of 32
  bf16x8 qf[2];
#pragma unroll
  for (int i = 0; i < 2; ++i)
    qf[i] = *(const bf16x8*)&Qf[(((size_t)(m0 >> 5) + wm * 2 + i) * 64 + lane) * 8];

  f32x16 acc[2][2] = {};
  bf16x8 wfE[2], wfO[2];               // W1aug frags for even/odd kt (2 x 32-k blocks)
  bf16x8 aqE[2][2][2], aqO[2][2][2];   // GEMM A-quads [i][b][sb], even/odd parity

#define WLOAD(KT, WF)                                                           \
  { _Pragma("unroll")                                                           \
    for (int b = 0; b < 2; ++b)                                                 \
      WF[b] = *(const bf16x8*)&W1f[(((size_t)(KT) * 2 + b) * 64 + lane) * 8]; }

#define STAGE(P, B)                                                             \
  { _Pragma("unroll")                                                           \
    for (int i2 = 0; i2 < 8; ++i2) {                                            \
      int ch = i2 * 256 + tid, row = ch >> 4, slot = ch & 15;                   \
      gload_lds16(&W2b[(size_t)(n0 + row) * FFN + (P) * 128 + slot * 8],        \
                  &Bw[B][ch * 8]);                                              \
    } }

  // H^T = mfma(W1aug, qaug); relu; cvt_pk; permlane32_swap -> A-quads (registers)
#define HGEN(AQ, WF)                                                            \
  { _Pragma("unroll")                                                           \
    for (int i = 0; i < 2; ++i) {                                               \
      _Pragma("unroll")                                                         \
      for (int b = 0; b < 2; ++b) {                                             \
        f32x16 zz = {};                                                         \
        f32x16 d = __builtin_amdgcn_mfma_f32_32x32x16_bf16(WF[b], qf[i], zz, 0, 0, 0); \
        u32 dw0, dw1, dw2, dw3, dw4, dw5, dw6, dw7;                             \
        { float a0=fmaxf(d[0],0.f),a1=fmaxf(d[1],0.f);                          \
          asm("v_cvt_pk_bf16_f32 %0, %1, %2":"=v"(dw0):"v"(a0),"v"(a1)); }      \
        { float a0=fmaxf(d[2],0.f),a1=fmaxf(d[3],0.f);                          \
          asm("v_cvt_pk_bf16_f32 %0, %1, %2":"=v"(dw1):"v"(a0),"v"(a1)); }      \
        { float a0=fmaxf(d[4],0.f),a1=fmaxf(d[5],0.f);                          \
          asm("v_cvt_pk_bf16_f32 %0, %1, %2":"=v"(dw2):"v"(a0),"v"(a1)); }      \
        { float a0=fmaxf(d[6],0.f),a1=fmaxf(d[7],0.f);                          \
          asm("v_cvt_pk_bf16_f32 %0, %1, %2":"=v"(dw3):"v"(a0),"v"(a1)); }      \
        { float a0=fmaxf(d[8],0.f),a1=fmaxf(d[9],0.f);                          \
          asm("v_cvt_pk_bf16_f32 %0, %1, %2":"=v"(dw4):"v"(a0),"v"(a1)); }      \
        { float a0=fmaxf(d[10],0.f),a1=fmaxf(d[11],0.f);                        \
          asm("v_cvt_pk_bf16_f32 %0, %1, %2":"=v"(dw5):"v"(a0),"v"(a1)); }      \
        { float a0=fmaxf(d[12],0.f),a1=fmaxf(d[13],0.f);                        \
          asm("v_cvt_pk_bf16_f32 %0, %1, %2":"=v"(dw6):"v"(a0),"v"(a1)); }      \
        { float a0=fmaxf(d[14],0.f),a1=fmaxf(d[15],0.f);                        \
          asm("v_cvt_pk_bf16_f32 %0, %1, %2":"=v"(dw7):"v"(a0),"v"(a1)); }      \
        asm("v_permlane32_swap_b32 %0, %1" : "+v"(dw0), "+v"(dw2));             \
        asm("v_permlane32_swap_b32 %0, %1" : "+v"(dw1), "+v"(dw3));             \
        asm("v_permlane32_swap_b32 %0, %1" : "+v"(dw4), "+v"(dw6));             \
        asm("v_permlane32_swap_b32 %0, %1" : "+v"(dw5), "+v"(dw7));             \
        union { u32 u[4]; bf16x8 v; } u0, u1;                                   \
        u0.u[0]=dw0; u0.u[1]=dw1; u0.u[2]=dw2; u0.u[3]=dw3;                     \
        u1.u[0]=dw4; u1.u[1]=dw5; u1.u[2]=dw6; u1.u[3]=dw7;                     \
        AQ[i][b][0] = u0.v; AQ[i][b][1] = u1.v;                                 \
      } } }

#define GEMMKT(KPAR, AQ, BUF)                                                   \
  { _Pragma("unroll")                                                           \
    for (int b = 0; b < 2; ++b) {                                               \
      _Pragma("unroll")                                                         \
      for (int sb = 0; sb < 2; ++sb) {                                          \
        bf16x8 bg0, bg1;                                                        \
        { int row = wn * 64 + t31;                                              \
          int c = (KPAR) * 8 + b * 4 + sb * 2 + h;                              \
          bg0 = *(const bf16x8*)((const char*)&Bw[BUF][0] + row * 256 +         \
                                 (c ^ (row & 15)) * 16); }                      \
        { int row = wn * 64 + 32 + t31;                                         \
          int c = (KPAR) * 8 + b * 4 + sb * 2 + h;                              \
          bg1 = *(const bf16x8*)((const char*)&Bw[BUF][0] + row * 256 +         \
                                 (c ^ (row & 15)) * 16); }                      \
        __builtin_amdgcn_s_setprio(1);                                          \
        acc[0][0] = __builtin_amdgcn_mfma_f32_32x32x16_bf16(AQ[0][b][sb], bg0, acc[0][0], 0, 0, 0); \
        acc[0][1] = __builtin_amdgcn_mfma_f32_32x32x16_bf16(AQ[0][b][sb], bg1, acc[0][1], 0, 0, 0); \
        acc[1][0] = __builtin_amdgcn_mfma_f32_32x32x16_bf16(AQ[1][b][sb], bg0, acc[1][0], 0, 0, 0); \
        acc[1][1] = __builtin_amdgcn_mfma_f32_32x32x16_bf16(AQ[1][b][sb], bg1, acc[1][1], 0, 0, 0); \
        __builtin_amdgcn_s_setprio(0);                                          \
      } } }

  // ---- prologue ----
  WLOAD(0, wfE);
  WLOAD(1, wfO);
  STAGE(0, 0);
  STAGE(1, 1);
  HGEN(aqE, wfE);                      // A-quads for kt=0 (compiler waits the loads)

  // ---- main loop: one K-pair (2 K-tiles) per iteration ----
  for (int p = 0; p < 16; ++p) {
    asm volatile("s_waitcnt vmcnt(0)" ::: "memory");   // pair p landed
    __builtin_amdgcn_s_barrier();                      // all waves done with pair p-1 buf
    if (p < 15) STAGE(p + 1, (p + 1) & 1);             // post-barrier issue: race-safe
    const int buf = p & 1;
    // kt = 2p (even): GEMM on aqE, build aqO for kt+1
    if (p < 15) WLOAD(2 * p + 2, wfE);
    GEMMKT(0, aqE, buf);
    HGEN(aqO, wfO);
    // kt = 2p+1 (odd): GEMM on aqO, build aqE for kt+2
    if (p < 15) {
      WLOAD(2 * p + 3, wfO);
      GEMMKT(1, aqO, buf);
      HGEN(aqE, wfE);
    } else {
      GEMMKT(1, aqO, buf);
    }
  }

  // ---- epilogue: out = acc + b2 ----
#pragma unroll
  for (int j = 0; j < 2; ++j) {
    const int col = n0 + wn * 64 + j * 32 + t31;
    const float bbv = b2[col];
#pragma unroll
    for (int i = 0; i < 2; ++i) {
#pragma unroll
      for (int r = 0; r < 16; ++r) {
        int tok = m0 + wm * 64 + i * 32 + (r & 3) + 8 * (r >> 2) + 4 * h;
        out[(size_t)tok * EMBED + col] = acc[i][j][r] + bbv;
      }
    }
  }
#undef WLOAD
#undef STAGE
#undef HGEN
#undef GEMMKT
}

extern "C" void kernel_launch(void* const* d_in, const int* in_sizes, int n_in,
                              void* d_out, int out_size, void* d_ws, size_t ws_size,
                              hipStream_t stream) {
  const float* x     = (const float*)d_in[0];
  const float* theta = (const float*)d_in[1];
  const float* W1    = (const float*)d_in[2];
  const float* b1    = (const float*)d_in[3];
  const float* W2    = (const float*)d_in[4];
  const float* b2    = (const float*)d_in[5];
  float* out = (float*)d_out;

  char* ws = (char*)d_ws;
  unsigned short* W2b = (unsigned short*)ws;                          // 2 MB
  unsigned short* W1f = (unsigned short*)(ws + (2u << 20));           // 64 KB
  unsigned short* Qfg = (unsigned short*)(ws + (2u << 20) + (64u << 10)); // 512 KB

  k_cvt_w2 <<<(EMBED * FFN) / (256 * 8), 256, 0, stream>>>(W2, W2b);
  k_cvt_w1f<<<16, 256, 0, stream>>>(W1, b1, W1f);
  k_q      <<<128, 256, 0, stream>>>(x, theta, Qfg);
  k_fused  <<<(NTOK / BM) * (EMBED / BN), 256, 0, stream>>>(Qfg, W1f, W2b, b2, out);
}